// Round 4
// baseline (2963.934 us; speedup 1.0000x reference)
//
#include <hip/hip_runtime.h>

#define GAMMA 0.1f
#define EPS_F 1e-12f

// ---- partition-scan configuration ----
// 20000 nodes/partition * sizeof(float2) = 160000 B LDS (gfx950 has 160 KiB/CU)
#define S_NODES 20000
#define SCAN_THREADS 1024
#define B_TARGET 51   // chunks per partition; P=5 -> grid 255 blocks (~1/CU)

// ---------------- path A: bucket edges by dst-partition, then dense scan ----

__global__ void zero_kernel(int* __restrict__ cnt, int P) {
    int i = threadIdx.x;
    if (i < P) cnt[i] = 0;
}

// stream indices once; wave-aggregated scatter of (src,dst) into P buckets
__global__ __launch_bounds__(1024)
void bucket_kernel(const int4* __restrict__ src4,
                   const int4* __restrict__ dst4,
                   const int* __restrict__ src,
                   const int* __restrict__ dst,
                   int2* __restrict__ buckets,
                   int* __restrict__ cnt_g,
                   long cap, int e, int P) {
    int e4 = e >> 2;
    int gid = blockIdx.x * blockDim.x + threadIdx.x;
    int gstride = gridDim.x * blockDim.x;
    int lane = threadIdx.x & 63;
    unsigned long long lmask_lt = (lane == 63) ? 0x7fffffffffffffffull
                                               : ((1ull << lane) - 1ull);
    for (int i = gid; i < e4; i += gstride) {
        int4 s4 = src4[i];
        int4 d4 = dst4[i];
        #pragma unroll
        for (int c = 0; c < 4; ++c) {
            int s = (c == 0) ? s4.x : (c == 1) ? s4.y : (c == 2) ? s4.z : s4.w;
            int d = (c == 0) ? d4.x : (c == 1) ? d4.y : (c == 2) ? d4.z : d4.w;
            int p = d / S_NODES;
            for (int k = 0; k < P; ++k) {
                unsigned long long m = __ballot(p == k);
                if (m) {
                    int leader = __ffsll((long long)m) - 1;
                    int base = 0;
                    if (lane == leader)
                        base = atomicAdd(&cnt_g[k], __popcll(m));
                    base = __shfl(base, leader);
                    if (p == k) {
                        long idx = (long)base + __popcll(m & lmask_lt);
                        if (idx < cap)
                            buckets[(long)k * cap + idx] = make_int2(s, d);
                    }
                }
            }
        }
    }
    // tail (e % 4 edges)
    if (gid == 0) {
        for (int i = e4 * 4; i < e; ++i) {
            int d = dst[i];
            int p = d / S_NODES;
            int base = atomicAdd(&cnt_g[p], 1);
            if (base < cap)
                buckets[(long)p * cap + base] = make_int2(src[i], d);
        }
    }
}

// dense per-partition scan: every edge is in-partition (100% lane-active)
__global__ __launch_bounds__(SCAN_THREADS, 1)
void scan2_kernel(const float2* __restrict__ x,
                  const int2* __restrict__ buckets,
                  const int* __restrict__ cnt_g,
                  long cap,
                  float2* __restrict__ partials,
                  int B) {
    __shared__ float2 acc[S_NODES];
    int p = blockIdx.x / B;
    int b = blockIdx.x - p * B;
    int lo = p * S_NODES;
    int tid = threadIdx.x;

    for (int i = tid; i < S_NODES; i += SCAN_THREADS)
        acc[i] = make_float2(0.f, 0.f);
    __syncthreads();

    int cnt = cnt_g[p];
    if (cnt > (int)cap) cnt = (int)cap;
    const int4* eb = (const int4*)(buckets + (long)p * cap);  // 2 edges per int4
    int g = (cnt + 1) >> 1;
    int gchunk = (g + B - 1) / B;
    int gs = b * gchunk;
    int ge = min(gs + gchunk, g);

    for (int i = gs + tid; i < ge; i += SCAN_THREADS) {
        int4 t = eb[i];
        {   // edge 2i : (t.x = src, t.y = dst) — always valid since 2i < cnt
            int s = t.x, d = t.y;
            float2 xs = x[s];
            float2 xd = x[d];
            float dx = xd.x - xs.x;
            float dy = xd.y - xs.y;
            float r = sqrtf(dx * dx + dy * dy);
            float sc = -2.0f * (r - 1.0f) / fmaxf(r, EPS_F);
            atomicAdd(&acc[d - lo].x, sc * dx);
            atomicAdd(&acc[d - lo].y, sc * dy);
        }
        if (2 * i + 1 < cnt) {  // edge 2i+1 : (t.z, t.w)
            int s = t.z, d = t.w;
            float2 xs = x[s];
            float2 xd = x[d];
            float dx = xd.x - xs.x;
            float dy = xd.y - xs.y;
            float r = sqrtf(dx * dx + dy * dy);
            float sc = -2.0f * (r - 1.0f) / fmaxf(r, EPS_F);
            atomicAdd(&acc[d - lo].x, sc * dx);
            atomicAdd(&acc[d - lo].y, sc * dy);
        }
    }
    __syncthreads();

    float2* wsb = partials + (size_t)blockIdx.x * S_NODES;
    for (int i = tid; i < S_NODES; i += SCAN_THREADS)
        wsb[i] = acc[i];
}

__global__ __launch_bounds__(256)
void reduce_kernel(const float2* __restrict__ partials,
                   const float2* __restrict__ v,
                   float2* __restrict__ out,
                   int n, int B) {
    int i = blockIdx.x * blockDim.x + threadIdx.x;
    if (i >= n) return;
    int p = i / S_NODES;
    int loc = i - p * S_NODES;
    const float2* base = partials + ((size_t)(p * B) * S_NODES + loc);
    float sx0 = 0.f, sy0 = 0.f, sx1 = 0.f, sy1 = 0.f;
    float sx2 = 0.f, sy2 = 0.f, sx3 = 0.f, sy3 = 0.f;
    int b = 0;
    for (; b + 8 <= B; b += 8) {
        float2 t0 = base[(size_t)(b + 0) * S_NODES];
        float2 t1 = base[(size_t)(b + 1) * S_NODES];
        float2 t2 = base[(size_t)(b + 2) * S_NODES];
        float2 t3 = base[(size_t)(b + 3) * S_NODES];
        float2 t4 = base[(size_t)(b + 4) * S_NODES];
        float2 t5 = base[(size_t)(b + 5) * S_NODES];
        float2 t6 = base[(size_t)(b + 6) * S_NODES];
        float2 t7 = base[(size_t)(b + 7) * S_NODES];
        sx0 += t0.x; sy0 += t0.y; sx1 += t1.x; sy1 += t1.y;
        sx2 += t2.x; sy2 += t2.y; sx3 += t3.x; sy3 += t3.y;
        sx0 += t4.x; sy0 += t4.y; sx1 += t5.x; sy1 += t5.y;
        sx2 += t6.x; sy2 += t6.y; sx3 += t7.x; sy3 += t7.y;
    }
    for (; b < B; ++b) {
        float2 t = base[(size_t)b * S_NODES];
        sx0 += t.x; sy0 += t.y;
    }
    float sx = (sx0 + sx1) + (sx2 + sx3);
    float sy = (sy0 + sy1) + (sy2 + sy3);
    float2 vi = v[i];
    out[i] = make_float2(sx - GAMMA * vi.x, sy - GAMMA * vi.y);
}

// ---------------- path B: filtered scan (round-3 kernel, ws fallback) -------

#define EDGE(dd, ss) do {                                        \
    int d_ = (dd);                                               \
    if (d_ >= lo && d_ < hi) {                                   \
        float2 xs = x[(ss)];                                     \
        float2 xd = x[d_];                                       \
        float dx = xd.x - xs.x;                                  \
        float dy = xd.y - xs.y;                                  \
        float r = sqrtf(dx * dx + dy * dy);                      \
        float sc = -2.0f * (r - 1.0f) / fmaxf(r, EPS_F);         \
        atomicAdd(&acc[d_ - lo].x, sc * dx);                     \
        atomicAdd(&acc[d_ - lo].y, sc * dy);                     \
    }                                                            \
} while (0)

__global__ __launch_bounds__(SCAN_THREADS, 1)
void scan_kernel(const float2* __restrict__ x,
                 const int4* __restrict__ src4,
                 const int4* __restrict__ dst4,
                 const int* __restrict__ src,
                 const int* __restrict__ dst,
                 float2* __restrict__ ws,
                 int e, int n, int B, int chunk) {
    __shared__ float2 acc[S_NODES];
    int p = blockIdx.x / B;
    int b = blockIdx.x - p * B;
    int lo = p * S_NODES;
    int hi = min(lo + S_NODES, n);
    int tid = threadIdx.x;

    for (int i = tid; i < S_NODES; i += SCAN_THREADS)
        acc[i] = make_float2(0.f, 0.f);
    __syncthreads();

    int estart = b * chunk;
    int eend = min(estart + chunk, e);
    if (estart < eend) {
        int nvec = (eend - estart) >> 2;
        const int4* d4p = dst4 + (estart >> 2);
        const int4* s4p = src4 + (estart >> 2);
        for (int i = tid; i < nvec; i += SCAN_THREADS) {
            int4 d4 = d4p[i];
            int4 s4 = s4p[i];
            EDGE(d4.x, s4.x);
            EDGE(d4.y, s4.y);
            EDGE(d4.z, s4.z);
            EDGE(d4.w, s4.w);
        }
        for (int i = estart + (nvec << 2) + tid; i < eend; i += SCAN_THREADS)
            EDGE(dst[i], src[i]);
    }
    __syncthreads();

    float2* wsb = ws + (size_t)blockIdx.x * S_NODES;
    for (int i = tid; i < S_NODES; i += SCAN_THREADS)
        wsb[i] = acc[i];
}

// ---------------- path C: direct global atomics (last resort) ---------------

__global__ void init_out_kernel(const float2* __restrict__ v,
                                float2* __restrict__ out, int n) {
    int i = blockIdx.x * blockDim.x + threadIdx.x;
    if (i < n) {
        float2 vi = v[i];
        out[i] = make_float2(-GAMMA * vi.x, -GAMMA * vi.y);
    }
}

__device__ __forceinline__ void do_edge_atomic(const float2* __restrict__ x,
                                               int s, int d,
                                               float* __restrict__ out) {
    float2 xs = x[s];
    float2 xd = x[d];
    float dx = xd.x - xs.x;
    float dy = xd.y - xs.y;
    float r = sqrtf(dx * dx + dy * dy);
    float sc = -2.0f * (r - 1.0f) / fmaxf(r, EPS_F);
    atomicAdd(&out[2 * d], sc * dx);
    atomicAdd(&out[2 * d + 1], sc * dy);
}

__global__ void edge_kernel_atomic(const float2* __restrict__ x,
                                   const int4* __restrict__ src4,
                                   const int4* __restrict__ dst4,
                                   const int* __restrict__ src,
                                   const int* __restrict__ dst,
                                   float* __restrict__ out,
                                   int e4, int e_total) {
    int i = blockIdx.x * blockDim.x + threadIdx.x;
    if (i < e4) {
        int4 s = src4[i];
        int4 d = dst4[i];
        do_edge_atomic(x, s.x, d.x, out);
        do_edge_atomic(x, s.y, d.y, out);
        do_edge_atomic(x, s.z, d.z, out);
        do_edge_atomic(x, s.w, d.w, out);
    }
    if (i == 0) {
        for (int e = e4 * 4; e < e_total; ++e)
            do_edge_atomic(x, src[e], dst[e], out);
    }
}

extern "C" void kernel_launch(void* const* d_in, const int* in_sizes, int n_in,
                              void* d_out, int out_size, void* d_ws, size_t ws_size,
                              hipStream_t stream) {
    const float2* x = (const float2*)d_in[0];   // [N,2] fp32
    const float2* v = (const float2*)d_in[1];   // [N,2] fp32
    const int* src  = (const int*)d_in[2];      // [E] int32
    const int* dst  = (const int*)d_in[3];      // [E] int32

    int n = in_sizes[0] / 2;   // N nodes
    int e = in_sizes[2];       // E edges

    float* out = (float*)d_out;

    int P = (n + S_NODES - 1) / S_NODES;
    int B = B_TARGET;

    // ws layout for path A: [counters(256B)] [buckets P*cap*8] [partials P*B*S_NODES*8]
    long cap = (long)(e / P) + (long)(e / (P * 8)) + 1024;  // E/P + 12.5% margin
    cap = (cap + 1) & ~1l;                                  // even (int4 pairing)
    size_t off_buckets = 256;
    size_t sz_buckets = (size_t)P * (size_t)cap * sizeof(int2);
    size_t off_part = (off_buckets + sz_buckets + 255) & ~(size_t)255;
    size_t sz_part = (size_t)P * B * (size_t)S_NODES * sizeof(float2);
    size_t need_a = off_part + sz_part;

    if (ws_size >= need_a) {
        int* cnt_g = (int*)d_ws;
        int2* buckets = (int2*)((char*)d_ws + off_buckets);
        float2* partials = (float2*)((char*)d_ws + off_part);

        zero_kernel<<<1, 64, 0, stream>>>(cnt_g, P);
        bucket_kernel<<<256, 1024, 0, stream>>>(
            (const int4*)src, (const int4*)dst, src, dst,
            buckets, cnt_g, cap, e, P);
        scan2_kernel<<<P * B, SCAN_THREADS, 0, stream>>>(
            x, buckets, cnt_g, cap, partials, B);
        reduce_kernel<<<(n + 255) / 256, 256, 0, stream>>>(
            partials, v, (float2*)out, n, B);
    } else if (ws_size >= sz_part) {
        // path B: filtered scan (P passes over indices)
        int chunk = (((e + B - 1) / B) + 3) & ~3;
        scan_kernel<<<P * B, SCAN_THREADS, 0, stream>>>(
            x, (const int4*)src, (const int4*)dst, src, dst,
            (float2*)d_ws, e, n, B, chunk);
        reduce_kernel<<<(n + 255) / 256, 256, 0, stream>>>(
            (const float2*)d_ws, v, (float2*)out, n, B);
    } else {
        // path C: direct atomics
        int threads = 256;
        init_out_kernel<<<(n + threads - 1) / threads, threads, 0, stream>>>(
            v, (float2*)out, n);
        int e4 = e / 4;
        int blocks = (e4 + threads - 1) / threads;
        if (blocks < 1) blocks = 1;
        edge_kernel_atomic<<<blocks, threads, 0, stream>>>(
            x, (const int4*)src, (const int4*)dst, src, dst, out, e4, e);
    }
}

// Round 5
// 155.341 us; speedup vs baseline: 19.0802x; 19.0802x over previous
//
#include <hip/hip_runtime.h>

#define GAMMA 0.1f
#define EPS_F 1e-12f

// ---- partition-scan configuration ----
// 20000 nodes/partition * sizeof(float2) = 160000 B LDS (gfx950 has 160 KiB/CU)
#define S_NODES 20000
#define SCAN_THREADS 1024
#define B_TARGET 51     // chunks per partition; P=5 -> grid 255 blocks (~1/CU)
#define BK_BLOCKS 256   // bucket kernel grid

// ---------------- path A: bucket edges by dst-partition, then dense scan ----

__global__ void zero_kernel(int* __restrict__ cnt, int P) {
    int i = threadIdx.x;
    if (i < P) cnt[i] = 0;
}

// Two-phase per-block scatter. Global atomics: ONE per partition per block
// (5*256 = 1280 total). All fine-grained aggregation is LDS. (Round-4 version
// did ~250K serialized same-address GLOBAL atomics -> 2.8 ms.)
__global__ __launch_bounds__(1024)
void bucket_kernel(const int4* __restrict__ src4,
                   const int4* __restrict__ dst4,
                   const int* __restrict__ src,
                   const int* __restrict__ dst,
                   int2* __restrict__ buckets,
                   int* __restrict__ cnt_g,
                   long cap, int e, int P, int chunk) {
    __shared__ int blk_cnt[8];    // per-partition count for this block
    __shared__ int blk_off[8];    // running write offset (seeded with global base)
    int tid = threadIdx.x;
    int lane = tid & 63;
    unsigned long long lmask_lt = (1ull << lane) - 1ull;  // lane 63: 1<<63-1 ok

    if (tid < 8) blk_cnt[tid] = 0;
    __syncthreads();

    int e4 = e >> 2;
    long gstart = (long)blockIdx.x * chunk;        // in int4 groups
    long gend = gstart + chunk;
    if (gend > e4) gend = e4;

    // ---- pass 1: count per-partition edges in this block's chunk ----
    for (long i = gstart + tid; i < gend; i += 1024) {
        int4 d4 = dst4[i];
        #pragma unroll
        for (int c = 0; c < 4; ++c) {
            int d = (c == 0) ? d4.x : (c == 1) ? d4.y : (c == 2) ? d4.z : d4.w;
            int p = d / S_NODES;
            for (int k = 0; k < P; ++k) {
                unsigned long long m = __ballot(p == k);
                if (m) {
                    int leader = __ffsll((long long)m) - 1;  // active lane
                    if (lane == leader)
                        atomicAdd(&blk_cnt[k], __popcll(m));
                }
            }
        }
    }
    __syncthreads();

    // ---- reserve global ranges: 1 global atomic per partition per block ----
    if (tid < P)
        blk_off[tid] = atomicAdd(&cnt_g[tid], blk_cnt[tid]);
    __syncthreads();

    // ---- pass 2: rank-ordered scatter via LDS offset counters ----
    for (long i = gstart + tid; i < gend; i += 1024) {
        int4 s4 = src4[i];
        int4 d4 = dst4[i];
        #pragma unroll
        for (int c = 0; c < 4; ++c) {
            int s = (c == 0) ? s4.x : (c == 1) ? s4.y : (c == 2) ? s4.z : s4.w;
            int d = (c == 0) ? d4.x : (c == 1) ? d4.y : (c == 2) ? d4.z : d4.w;
            int p = d / S_NODES;
            for (int k = 0; k < P; ++k) {
                unsigned long long m = __ballot(p == k);
                if (m) {
                    int leader = __ffsll((long long)m) - 1;
                    int base = 0;
                    if (lane == leader)
                        base = atomicAdd(&blk_off[k], __popcll(m));
                    base = __shfl(base, leader);
                    if (p == k) {
                        long idx = (long)base + __popcll(m & lmask_lt);
                        if (idx < cap)
                            buckets[(long)k * cap + idx] = make_int2(s, d);
                    }
                }
            }
        }
    }

    // tail (e % 4 edges) — E=3.2M is 4-divisible; kept for generality
    if (blockIdx.x == 0 && tid == 0) {
        for (int i = e4 * 4; i < e; ++i) {
            int d = dst[i];
            int p = d / S_NODES;
            int base = atomicAdd(&cnt_g[p], 1);
            if (base < cap)
                buckets[(long)p * cap + base] = make_int2(src[i], d);
        }
    }
}

// dense per-partition scan: every edge is in-partition (100% lane-active)
__global__ __launch_bounds__(SCAN_THREADS, 1)
void scan2_kernel(const float2* __restrict__ x,
                  const int2* __restrict__ buckets,
                  const int* __restrict__ cnt_g,
                  long cap,
                  float2* __restrict__ partials,
                  int B) {
    __shared__ float2 acc[S_NODES];
    int p = blockIdx.x / B;
    int b = blockIdx.x - p * B;
    int lo = p * S_NODES;
    int tid = threadIdx.x;

    for (int i = tid; i < S_NODES; i += SCAN_THREADS)
        acc[i] = make_float2(0.f, 0.f);
    __syncthreads();

    int cnt = cnt_g[p];
    if (cnt > (int)cap) cnt = (int)cap;
    const int4* eb = (const int4*)(buckets + (long)p * cap);  // 2 edges per int4
    int g = (cnt + 1) >> 1;
    int gchunk = (g + B - 1) / B;
    int gs = b * gchunk;
    int ge = min(gs + gchunk, g);

    for (int i = gs + tid; i < ge; i += SCAN_THREADS) {
        int4 t = eb[i];
        {   // edge 2i : (t.x = src, t.y = dst) — always valid since 2i < cnt
            int s = t.x, d = t.y;
            float2 xs = x[s];
            float2 xd = x[d];
            float dx = xd.x - xs.x;
            float dy = xd.y - xs.y;
            float r = sqrtf(dx * dx + dy * dy);
            float sc = -2.0f * (r - 1.0f) / fmaxf(r, EPS_F);
            atomicAdd(&acc[d - lo].x, sc * dx);
            atomicAdd(&acc[d - lo].y, sc * dy);
        }
        if (2 * i + 1 < cnt) {  // edge 2i+1 : (t.z, t.w)
            int s = t.z, d = t.w;
            float2 xs = x[s];
            float2 xd = x[d];
            float dx = xd.x - xs.x;
            float dy = xd.y - xs.y;
            float r = sqrtf(dx * dx + dy * dy);
            float sc = -2.0f * (r - 1.0f) / fmaxf(r, EPS_F);
            atomicAdd(&acc[d - lo].x, sc * dx);
            atomicAdd(&acc[d - lo].y, sc * dy);
        }
    }
    __syncthreads();

    float2* wsb = partials + (size_t)blockIdx.x * S_NODES;
    for (int i = tid; i < S_NODES; i += SCAN_THREADS)
        wsb[i] = acc[i];
}

__global__ __launch_bounds__(256)
void reduce_kernel(const float2* __restrict__ partials,
                   const float2* __restrict__ v,
                   float2* __restrict__ out,
                   int n, int B) {
    int i = blockIdx.x * blockDim.x + threadIdx.x;
    if (i >= n) return;
    int p = i / S_NODES;
    int loc = i - p * S_NODES;
    const float2* base = partials + ((size_t)(p * B) * S_NODES + loc);
    float sx0 = 0.f, sy0 = 0.f, sx1 = 0.f, sy1 = 0.f;
    float sx2 = 0.f, sy2 = 0.f, sx3 = 0.f, sy3 = 0.f;
    int b = 0;
    for (; b + 8 <= B; b += 8) {
        float2 t0 = base[(size_t)(b + 0) * S_NODES];
        float2 t1 = base[(size_t)(b + 1) * S_NODES];
        float2 t2 = base[(size_t)(b + 2) * S_NODES];
        float2 t3 = base[(size_t)(b + 3) * S_NODES];
        float2 t4 = base[(size_t)(b + 4) * S_NODES];
        float2 t5 = base[(size_t)(b + 5) * S_NODES];
        float2 t6 = base[(size_t)(b + 6) * S_NODES];
        float2 t7 = base[(size_t)(b + 7) * S_NODES];
        sx0 += t0.x; sy0 += t0.y; sx1 += t1.x; sy1 += t1.y;
        sx2 += t2.x; sy2 += t2.y; sx3 += t3.x; sy3 += t3.y;
        sx0 += t4.x; sy0 += t4.y; sx1 += t5.x; sy1 += t5.y;
        sx2 += t6.x; sy2 += t6.y; sx3 += t7.x; sy3 += t7.y;
    }
    for (; b < B; ++b) {
        float2 t = base[(size_t)b * S_NODES];
        sx0 += t.x; sy0 += t.y;
    }
    float sx = (sx0 + sx1) + (sx2 + sx3);
    float sy = (sy0 + sy1) + (sy2 + sy3);
    float2 vi = v[i];
    out[i] = make_float2(sx - GAMMA * vi.x, sy - GAMMA * vi.y);
}

// ---------------- path B: filtered scan (ws fallback) -----------------------

#define EDGE(dd, ss) do {                                        \
    int d_ = (dd);                                               \
    if (d_ >= lo && d_ < hi) {                                   \
        float2 xs = x[(ss)];                                     \
        float2 xd = x[d_];                                       \
        float dx = xd.x - xs.x;                                  \
        float dy = xd.y - xs.y;                                  \
        float r = sqrtf(dx * dx + dy * dy);                      \
        float sc = -2.0f * (r - 1.0f) / fmaxf(r, EPS_F);         \
        atomicAdd(&acc[d_ - lo].x, sc * dx);                     \
        atomicAdd(&acc[d_ - lo].y, sc * dy);                     \
    }                                                            \
} while (0)

__global__ __launch_bounds__(SCAN_THREADS, 1)
void scan_kernel(const float2* __restrict__ x,
                 const int4* __restrict__ src4,
                 const int4* __restrict__ dst4,
                 const int* __restrict__ src,
                 const int* __restrict__ dst,
                 float2* __restrict__ ws,
                 int e, int n, int B, int chunk) {
    __shared__ float2 acc[S_NODES];
    int p = blockIdx.x / B;
    int b = blockIdx.x - p * B;
    int lo = p * S_NODES;
    int hi = min(lo + S_NODES, n);
    int tid = threadIdx.x;

    for (int i = tid; i < S_NODES; i += SCAN_THREADS)
        acc[i] = make_float2(0.f, 0.f);
    __syncthreads();

    int estart = b * chunk;
    int eend = min(estart + chunk, e);
    if (estart < eend) {
        int nvec = (eend - estart) >> 2;
        const int4* d4p = dst4 + (estart >> 2);
        const int4* s4p = src4 + (estart >> 2);
        for (int i = tid; i < nvec; i += SCAN_THREADS) {
            int4 d4 = d4p[i];
            int4 s4 = s4p[i];
            EDGE(d4.x, s4.x);
            EDGE(d4.y, s4.y);
            EDGE(d4.z, s4.z);
            EDGE(d4.w, s4.w);
        }
        for (int i = estart + (nvec << 2) + tid; i < eend; i += SCAN_THREADS)
            EDGE(dst[i], src[i]);
    }
    __syncthreads();

    float2* wsb = ws + (size_t)blockIdx.x * S_NODES;
    for (int i = tid; i < S_NODES; i += SCAN_THREADS)
        wsb[i] = acc[i];
}

// ---------------- path C: direct global atomics (last resort) ---------------

__global__ void init_out_kernel(const float2* __restrict__ v,
                                float2* __restrict__ out, int n) {
    int i = blockIdx.x * blockDim.x + threadIdx.x;
    if (i < n) {
        float2 vi = v[i];
        out[i] = make_float2(-GAMMA * vi.x, -GAMMA * vi.y);
    }
}

__device__ __forceinline__ void do_edge_atomic(const float2* __restrict__ x,
                                               int s, int d,
                                               float* __restrict__ out) {
    float2 xs = x[s];
    float2 xd = x[d];
    float dx = xd.x - xs.x;
    float dy = xd.y - xs.y;
    float r = sqrtf(dx * dx + dy * dy);
    float sc = -2.0f * (r - 1.0f) / fmaxf(r, EPS_F);
    atomicAdd(&out[2 * d], sc * dx);
    atomicAdd(&out[2 * d + 1], sc * dy);
}

__global__ void edge_kernel_atomic(const float2* __restrict__ x,
                                   const int4* __restrict__ src4,
                                   const int4* __restrict__ dst4,
                                   const int* __restrict__ src,
                                   const int* __restrict__ dst,
                                   float* __restrict__ out,
                                   int e4, int e_total) {
    int i = blockIdx.x * blockDim.x + threadIdx.x;
    if (i < e4) {
        int4 s = src4[i];
        int4 d = dst4[i];
        do_edge_atomic(x, s.x, d.x, out);
        do_edge_atomic(x, s.y, d.y, out);
        do_edge_atomic(x, s.z, d.z, out);
        do_edge_atomic(x, s.w, d.w, out);
    }
    if (i == 0) {
        for (int e = e4 * 4; e < e_total; ++e)
            do_edge_atomic(x, src[e], dst[e], out);
    }
}

extern "C" void kernel_launch(void* const* d_in, const int* in_sizes, int n_in,
                              void* d_out, int out_size, void* d_ws, size_t ws_size,
                              hipStream_t stream) {
    const float2* x = (const float2*)d_in[0];   // [N,2] fp32
    const float2* v = (const float2*)d_in[1];   // [N,2] fp32
    const int* src  = (const int*)d_in[2];      // [E] int32
    const int* dst  = (const int*)d_in[3];      // [E] int32

    int n = in_sizes[0] / 2;   // N nodes
    int e = in_sizes[2];       // E edges

    float* out = (float*)d_out;

    int P = (n + S_NODES - 1) / S_NODES;
    int B = B_TARGET;

    // ws layout for path A: [counters(256B)] [buckets P*cap*8] [partials P*B*S_NODES*8]
    long cap = (long)(e / P) + (long)(e / (P * 8)) + 1024;  // E/P + 12.5% margin
    cap = (cap + 1) & ~1l;                                  // even (int4 pairing)
    size_t off_buckets = 256;
    size_t sz_buckets = (size_t)P * (size_t)cap * sizeof(int2);
    size_t off_part = (off_buckets + sz_buckets + 255) & ~(size_t)255;
    size_t sz_part = (size_t)P * B * (size_t)S_NODES * sizeof(float2);
    size_t need_a = off_part + sz_part;

    if (ws_size >= need_a && P <= 8) {
        int* cnt_g = (int*)d_ws;
        int2* buckets = (int2*)((char*)d_ws + off_buckets);
        float2* partials = (float2*)((char*)d_ws + off_part);

        int e4 = e >> 2;
        int chunk = (e4 + BK_BLOCKS - 1) / BK_BLOCKS;   // int4 groups per block

        zero_kernel<<<1, 64, 0, stream>>>(cnt_g, P);
        bucket_kernel<<<BK_BLOCKS, 1024, 0, stream>>>(
            (const int4*)src, (const int4*)dst, src, dst,
            buckets, cnt_g, cap, e, P, chunk);
        scan2_kernel<<<P * B, SCAN_THREADS, 0, stream>>>(
            x, buckets, cnt_g, cap, partials, B);
        reduce_kernel<<<(n + 255) / 256, 256, 0, stream>>>(
            partials, v, (float2*)out, n, B);
    } else if (ws_size >= sz_part) {
        // path B: filtered scan (P passes over indices)
        int chunk = (((e + B - 1) / B) + 3) & ~3;
        scan_kernel<<<P * B, SCAN_THREADS, 0, stream>>>(
            x, (const int4*)src, (const int4*)dst, src, dst,
            (float2*)d_ws, e, n, B, chunk);
        reduce_kernel<<<(n + 255) / 256, 256, 0, stream>>>(
            (const float2*)d_ws, v, (float2*)out, n, B);
    } else {
        // path C: direct atomics
        int threads = 256;
        init_out_kernel<<<(n + threads - 1) / threads, threads, 0, stream>>>(
            v, (float2*)out, n);
        int e4 = e / 4;
        int blocks = (e4 + threads - 1) / threads;
        if (blocks < 1) blocks = 1;
        edge_kernel_atomic<<<blocks, threads, 0, stream>>>(
            x, (const int4*)src, (const int4*)dst, src, dst, out, e4, e);
    }
}

// Round 6
// 152.648 us; speedup vs baseline: 19.4168x; 1.0176x over previous
//
#include <hip/hip_runtime.h>

#define GAMMA 0.1f
#define EPS_F 1e-12f

// ---- fine-grained partition config ----
// S_NODES=200 -> d_local fits in 8 bits; s (<2^17) packed above it: 25 bits/edge.
// P = ceil(100000/200) = 500 partitions; one scan block OWNS one partition:
// no partials, no reduce, out written exactly once.
#define S_NODES 200
#define PMAX 512          // power of two >= P (LDS scan width)
#define BK 256            // count/scatter grid
#define BK_THREADS 1024

// ---------------- 1) per-block per-partition histogram ----------------------
__global__ __launch_bounds__(BK_THREADS)
void count_kernel(const int4* __restrict__ dst4, const int* __restrict__ dst,
                  int* __restrict__ cnts, int e, int P, int chunk) {
    __shared__ int hist[PMAX];
    int tid = threadIdx.x, b = blockIdx.x;
    for (int i = tid; i < PMAX; i += BK_THREADS) hist[i] = 0;
    __syncthreads();
    int e4 = e >> 2;
    long gs = (long)b * chunk;
    long ge = gs + chunk; if (ge > e4) ge = e4;
    for (long i = gs + tid; i < ge; i += BK_THREADS) {
        int4 d4 = dst4[i];
        atomicAdd(&hist[d4.x / S_NODES], 1);
        atomicAdd(&hist[d4.y / S_NODES], 1);
        atomicAdd(&hist[d4.z / S_NODES], 1);
        atomicAdd(&hist[d4.w / S_NODES], 1);
    }
    if (b == BK - 1) {                       // tail edges (e % 4)
        for (int i = e4 * 4 + tid; i < e; i += BK_THREADS)
            atomicAdd(&hist[dst[i] / S_NODES], 1);
    }
    __syncthreads();
    for (int k = tid; k < PMAX; k += BK_THREADS)
        cnts[(long)b * PMAX + k] = hist[k];  // [b][k] layout: coalesced both ways
}

// ---------------- 2) exact offsets (single block, no global atomics) --------
__global__ __launch_bounds__(PMAX)
void offset_kernel(int* __restrict__ cnts, int* __restrict__ starts,
                   int e, int P) {
    __shared__ int sc[PMAX];
    int k = threadIdx.x;
    int total = 0;
    if (k < P)
        for (int b = 0; b < BK; ++b) total += cnts[(long)b * PMAX + k];
    sc[k] = total;
    __syncthreads();
    // Hillis-Steele inclusive scan over PMAX entries
    for (int off = 1; off < PMAX; off <<= 1) {
        int vv = (k >= off) ? sc[k - off] : 0;
        __syncthreads();
        sc[k] += vv;
        __syncthreads();
    }
    int start = sc[k] - total;               // exclusive prefix
    if (k < P) {
        starts[k] = start;
        if (k == P - 1) starts[P] = start + total;   // == e
        int run = start;                      // rewrite cnts -> absolute bases
        for (int b = 0; b < BK; ++b) {
            int c = cnts[(long)b * PMAX + k];
            cnts[(long)b * PMAX + k] = run;
            run += c;
        }
    }
}

// ---------------- 3) perfect-pack scatter (packed 4B edges) -----------------
__device__ __forceinline__ void scatter_one(int s, int d, int* loff,
                                            int* __restrict__ buckets) {
    int p = d / S_NODES;
    int r = atomicAdd(&loff[p], 1);          // LDS rank
    buckets[r] = (s << 8) | (d - p * S_NODES);
}

__global__ __launch_bounds__(BK_THREADS)
void scatter_kernel(const int4* __restrict__ src4, const int4* __restrict__ dst4,
                    const int* __restrict__ src, const int* __restrict__ dst,
                    const int* __restrict__ cnts, int* __restrict__ buckets,
                    int e, int P, int chunk) {
    __shared__ int loff[PMAX];
    int tid = threadIdx.x, b = blockIdx.x;
    for (int i = tid; i < PMAX; i += BK_THREADS)
        loff[i] = cnts[(long)b * PMAX + i];
    __syncthreads();
    int e4 = e >> 2;
    long gs = (long)b * chunk;
    long ge = gs + chunk; if (ge > e4) ge = e4;
    for (long i = gs + tid; i < ge; i += BK_THREADS) {
        int4 s4 = src4[i];
        int4 d4 = dst4[i];
        scatter_one(s4.x, d4.x, loff, buckets);
        scatter_one(s4.y, d4.y, loff, buckets);
        scatter_one(s4.z, d4.z, loff, buckets);
        scatter_one(s4.w, d4.w, loff, buckets);
    }
    if (b == BK - 1) {                       // tail edges: same block as count
        for (int i = e4 * 4 + tid; i < e; i += BK_THREADS)
            scatter_one(src[i], dst[i], loff, buckets);
    }
}

// ---------------- 4) dense scan: one block per partition, direct out --------
__global__ __launch_bounds__(1024)
void scan_kernel(const float2* __restrict__ x, const float2* __restrict__ v,
                 const int* __restrict__ buckets, const int* __restrict__ starts,
                 float2* __restrict__ out, int n) {
    __shared__ float2 acc[S_NODES];
    int k = blockIdx.x, tid = threadIdx.x;
    int lo = k * S_NODES;
    for (int i = tid; i < S_NODES; i += 1024) acc[i] = make_float2(0.f, 0.f);
    __syncthreads();
    int s0 = starts[k], s1 = starts[k + 1];
    for (int i = s0 + tid; i < s1; i += 1024) {
        int w = buckets[i];                  // coalesced 4B packed edge
        int s = w >> 8;
        int dl = w & 255;
        float2 xs = x[s];                    // random, L2-resident (800 KB)
        float2 xd = x[lo + dl];              // 1.6 KB window, L1
        float dx = xd.x - xs.x;
        float dy = xd.y - xs.y;
        float r = sqrtf(dx * dx + dy * dy);
        float sc = -2.0f * (r - 1.0f) / fmaxf(r, EPS_F);
        atomicAdd(&acc[dl].x, sc * dx);
        atomicAdd(&acc[dl].y, sc * dy);
    }
    __syncthreads();
    for (int i = tid; i < S_NODES; i += 1024) {
        int g = lo + i;
        if (g < n) {
            float2 vi = v[g];
            out[g] = make_float2(acc[i].x - GAMMA * vi.x,
                                 acc[i].y - GAMMA * vi.y);
        }
    }
}

// ---------------- fallback: direct global atomics ---------------------------
__global__ void init_out_kernel(const float2* __restrict__ v,
                                float2* __restrict__ out, int n) {
    int i = blockIdx.x * blockDim.x + threadIdx.x;
    if (i < n) {
        float2 vi = v[i];
        out[i] = make_float2(-GAMMA * vi.x, -GAMMA * vi.y);
    }
}

__device__ __forceinline__ void do_edge_atomic(const float2* __restrict__ x,
                                               int s, int d,
                                               float* __restrict__ out) {
    float2 xs = x[s];
    float2 xd = x[d];
    float dx = xd.x - xs.x;
    float dy = xd.y - xs.y;
    float r = sqrtf(dx * dx + dy * dy);
    float sc = -2.0f * (r - 1.0f) / fmaxf(r, EPS_F);
    atomicAdd(&out[2 * d], sc * dx);
    atomicAdd(&out[2 * d + 1], sc * dy);
}

__global__ void edge_kernel_atomic(const float2* __restrict__ x,
                                   const int4* __restrict__ src4,
                                   const int4* __restrict__ dst4,
                                   const int* __restrict__ src,
                                   const int* __restrict__ dst,
                                   float* __restrict__ out,
                                   int e4, int e_total) {
    int i = blockIdx.x * blockDim.x + threadIdx.x;
    if (i < e4) {
        int4 s = src4[i];
        int4 d = dst4[i];
        do_edge_atomic(x, s.x, d.x, out);
        do_edge_atomic(x, s.y, d.y, out);
        do_edge_atomic(x, s.z, d.z, out);
        do_edge_atomic(x, s.w, d.w, out);
    }
    if (i == 0) {
        for (int ee = e4 * 4; ee < e_total; ++ee)
            do_edge_atomic(x, src[ee], dst[ee], out);
    }
}

extern "C" void kernel_launch(void* const* d_in, const int* in_sizes, int n_in,
                              void* d_out, int out_size, void* d_ws, size_t ws_size,
                              hipStream_t stream) {
    const float2* x = (const float2*)d_in[0];   // [N,2] fp32
    const float2* v = (const float2*)d_in[1];   // [N,2] fp32
    const int* src  = (const int*)d_in[2];      // [E] int32
    const int* dst  = (const int*)d_in[3];      // [E] int32

    int n = in_sizes[0] / 2;   // N nodes
    int e = in_sizes[2];       // E edges

    float2* out = (float2*)d_out;

    int P = (n + S_NODES - 1) / S_NODES;

    // ws layout: [cnts BK*PMAX*4] [starts (PMAX+1)*4] [buckets e*4]
    size_t off_starts = (size_t)BK * PMAX * sizeof(int);
    size_t off_buckets = (off_starts + (PMAX + 1) * sizeof(int) + 255) & ~(size_t)255;
    size_t need = off_buckets + (size_t)e * sizeof(int);

    // s must fit 24 bits for the (s<<8 | d_local) packing
    if (P <= PMAX && n < (1 << 24) && ws_size >= need) {
        int* cnts = (int*)d_ws;
        int* starts = (int*)((char*)d_ws + off_starts);
        int* buckets = (int*)((char*)d_ws + off_buckets);

        int e4 = e >> 2;
        int chunk = (e4 + BK - 1) / BK;      // int4 groups per block

        count_kernel<<<BK, BK_THREADS, 0, stream>>>(
            (const int4*)dst, dst, cnts, e, P, chunk);
        offset_kernel<<<1, PMAX, 0, stream>>>(cnts, starts, e, P);
        scatter_kernel<<<BK, BK_THREADS, 0, stream>>>(
            (const int4*)src, (const int4*)dst, src, dst,
            cnts, buckets, e, P, chunk);
        scan_kernel<<<P, 1024, 0, stream>>>(
            x, v, buckets, starts, out, n);
    } else {
        // fallback: direct atomics
        int threads = 256;
        init_out_kernel<<<(n + threads - 1) / threads, threads, 0, stream>>>(
            v, out, n);
        int e4 = e / 4;
        int blocks = (e4 + threads - 1) / threads;
        if (blocks < 1) blocks = 1;
        edge_kernel_atomic<<<blocks, threads, 0, stream>>>(
            x, (const int4*)src, (const int4*)dst, src, dst, (float*)out, e4, e);
    }
}

// Round 7
// 138.886 us; speedup vs baseline: 21.3407x; 1.0991x over previous
//
#include <hip/hip_runtime.h>

#define GAMMA 0.1f
#define EPS_F 1e-12f

// ---- fine-grained partition config ----
// S_NODES=200 -> d_local fits in 8 bits; s (<2^17) packed above: 25 bits/edge.
// P = ceil(100000/200) = 500 partitions; one scan block OWNS one partition:
// no partials, no reduce, out written exactly once.
#define S_NODES 200
#define PMAX 512          // power of two >= P
#define BK 256            // count/scatter grid
#define BK_THREADS 1024

// ---------------- 1) per-block per-partition histogram ----------------------
// cnts layout: [k][b] (column-contiguous) so colscan reads coalesced.
__global__ __launch_bounds__(BK_THREADS)
void count_kernel(const int4* __restrict__ dst4, const int* __restrict__ dst,
                  int* __restrict__ cnts, int e, int chunk) {
    __shared__ int hist[PMAX];
    int tid = threadIdx.x, b = blockIdx.x;
    for (int i = tid; i < PMAX; i += BK_THREADS) hist[i] = 0;
    __syncthreads();
    int e4 = e >> 2;
    long gs = (long)b * chunk;
    long ge = gs + chunk; if (ge > e4) ge = e4;
    for (long i = gs + tid; i < ge; i += BK_THREADS) {
        int4 d4 = dst4[i];
        atomicAdd(&hist[d4.x / S_NODES], 1);
        atomicAdd(&hist[d4.y / S_NODES], 1);
        atomicAdd(&hist[d4.z / S_NODES], 1);
        atomicAdd(&hist[d4.w / S_NODES], 1);
    }
    if (b == BK - 1) {                       // tail edges (e % 4)
        for (int i = e4 * 4 + tid; i < e; i += BK_THREADS)
            atomicAdd(&hist[dst[i] / S_NODES], 1);
    }
    __syncthreads();
    for (int k = tid; k < PMAX; k += BK_THREADS)
        cnts[(long)k * BK + b] = hist[k];    // transposed: column k contiguous
}

// ---------------- 2a) per-column exclusive scan: one WAVE per column --------
__global__ __launch_bounds__(1024)
void colscan_kernel(int* __restrict__ cnts, int* __restrict__ totals) {
    int wid = (blockIdx.x * blockDim.x + threadIdx.x) >> 6;  // global wave id
    int lane = threadIdx.x & 63;
    if (wid >= PMAX) return;
    int4* col = (int4*)(cnts + (long)wid * BK);   // 256 ints = 64 lanes x int4
    int4 vv = col[lane];
    int lt = vv.x + vv.y + vv.z + vv.w;
    int inc = lt;                                 // inclusive wave scan
    #pragma unroll
    for (int off = 1; off < 64; off <<= 1) {
        int t = __shfl_up(inc, off);
        if (lane >= off) inc += t;
    }
    int ex = inc - lt;                            // exclusive prefix
    int4 bb;
    bb.x = ex;
    bb.y = ex + vv.x;
    bb.z = ex + vv.x + vv.y;
    bb.w = ex + vv.x + vv.y + vv.z;
    col[lane] = bb;                               // per-block local bases
    if (lane == 63) totals[wid] = inc;            // column total
}

// ---------------- 2b) cross-partition prefix (1 small block) ----------------
__global__ __launch_bounds__(PMAX)
void prefix_kernel(const int* __restrict__ totals, int* __restrict__ starts) {
    __shared__ int sc[PMAX];
    int k = threadIdx.x;
    int t = totals[k];
    sc[k] = t;
    __syncthreads();
    for (int off = 1; off < PMAX; off <<= 1) {
        int vv = (k >= off) ? sc[k - off] : 0;
        __syncthreads();
        sc[k] += vv;
        __syncthreads();
    }
    starts[k] = sc[k] - t;                        // exclusive
    if (k == PMAX - 1) starts[PMAX] = sc[k];      // == e
}

// ---------------- 3) perfect-pack scatter (packed 4B edges) -----------------
__device__ __forceinline__ void scatter_one(int s, int d, int* loff,
                                            int* __restrict__ buckets) {
    int p = d / S_NODES;
    int r = atomicAdd(&loff[p], 1);               // LDS rank
    buckets[r] = (s << 8) | (d - p * S_NODES);
}

__global__ __launch_bounds__(BK_THREADS)
void scatter_kernel(const int4* __restrict__ src4, const int4* __restrict__ dst4,
                    const int* __restrict__ src, const int* __restrict__ dst,
                    const int* __restrict__ cnts, const int* __restrict__ starts,
                    int* __restrict__ buckets, int e, int chunk) {
    __shared__ int loff[PMAX];
    int tid = threadIdx.x, b = blockIdx.x;
    for (int i = tid; i < PMAX; i += BK_THREADS)
        loff[i] = cnts[(long)i * BK + b] + starts[i];   // absolute base
    __syncthreads();
    int e4 = e >> 2;
    long gs = (long)b * chunk;
    long ge = gs + chunk; if (ge > e4) ge = e4;
    for (long i = gs + tid; i < ge; i += BK_THREADS) {
        int4 s4 = src4[i];
        int4 d4 = dst4[i];
        scatter_one(s4.x, d4.x, loff, buckets);
        scatter_one(s4.y, d4.y, loff, buckets);
        scatter_one(s4.z, d4.z, loff, buckets);
        scatter_one(s4.w, d4.w, loff, buckets);
    }
    if (b == BK - 1) {                       // tail edges: same block as count
        for (int i = e4 * 4 + tid; i < e; i += BK_THREADS)
            scatter_one(src[i], dst[i], loff, buckets);
    }
}

// ---------------- 4) dense scan: one block per partition, direct out --------
__global__ __launch_bounds__(1024)
void scan_kernel(const float2* __restrict__ x, const float2* __restrict__ v,
                 const int* __restrict__ buckets, const int* __restrict__ starts,
                 float2* __restrict__ out, int n) {
    __shared__ float2 acc[S_NODES];
    int k = blockIdx.x, tid = threadIdx.x;
    int lo = k * S_NODES;
    for (int i = tid; i < S_NODES; i += 1024) acc[i] = make_float2(0.f, 0.f);
    __syncthreads();
    int s0 = starts[k], s1 = starts[k + 1];
    for (int i = s0 + tid; i < s1; i += 1024) {
        int w = buckets[i];                  // coalesced 4B packed edge
        int s = w >> 8;
        int dl = w & 255;
        float2 xs = x[s];                    // random, L2-resident (800 KB)
        float2 xd = x[lo + dl];              // 1.6 KB window, L1
        float dx = xd.x - xs.x;
        float dy = xd.y - xs.y;
        float r = sqrtf(dx * dx + dy * dy);
        float sc = -2.0f * (r - 1.0f) / fmaxf(r, EPS_F);
        atomicAdd(&acc[dl].x, sc * dx);
        atomicAdd(&acc[dl].y, sc * dy);
    }
    __syncthreads();
    for (int i = tid; i < S_NODES; i += 1024) {
        int g = lo + i;
        if (g < n) {
            float2 vi = v[g];
            out[g] = make_float2(acc[i].x - GAMMA * vi.x,
                                 acc[i].y - GAMMA * vi.y);
        }
    }
}

// ---------------- fallback: direct global atomics ---------------------------
__global__ void init_out_kernel(const float2* __restrict__ v,
                                float2* __restrict__ out, int n) {
    int i = blockIdx.x * blockDim.x + threadIdx.x;
    if (i < n) {
        float2 vi = v[i];
        out[i] = make_float2(-GAMMA * vi.x, -GAMMA * vi.y);
    }
}

__device__ __forceinline__ void do_edge_atomic(const float2* __restrict__ x,
                                               int s, int d,
                                               float* __restrict__ out) {
    float2 xs = x[s];
    float2 xd = x[d];
    float dx = xd.x - xs.x;
    float dy = xd.y - xs.y;
    float r = sqrtf(dx * dx + dy * dy);
    float sc = -2.0f * (r - 1.0f) / fmaxf(r, EPS_F);
    atomicAdd(&out[2 * d], sc * dx);
    atomicAdd(&out[2 * d + 1], sc * dy);
}

__global__ void edge_kernel_atomic(const float2* __restrict__ x,
                                   const int4* __restrict__ src4,
                                   const int4* __restrict__ dst4,
                                   const int* __restrict__ src,
                                   const int* __restrict__ dst,
                                   float* __restrict__ out,
                                   int e4, int e_total) {
    int i = blockIdx.x * blockDim.x + threadIdx.x;
    if (i < e4) {
        int4 s = src4[i];
        int4 d = dst4[i];
        do_edge_atomic(x, s.x, d.x, out);
        do_edge_atomic(x, s.y, d.y, out);
        do_edge_atomic(x, s.z, d.z, out);
        do_edge_atomic(x, s.w, d.w, out);
    }
    if (i == 0) {
        for (int ee = e4 * 4; ee < e_total; ++ee)
            do_edge_atomic(x, src[ee], dst[ee], out);
    }
}

extern "C" void kernel_launch(void* const* d_in, const int* in_sizes, int n_in,
                              void* d_out, int out_size, void* d_ws, size_t ws_size,
                              hipStream_t stream) {
    const float2* x = (const float2*)d_in[0];   // [N,2] fp32
    const float2* v = (const float2*)d_in[1];   // [N,2] fp32
    const int* src  = (const int*)d_in[2];      // [E] int32
    const int* dst  = (const int*)d_in[3];      // [E] int32

    int n = in_sizes[0] / 2;   // N nodes
    int e = in_sizes[2];       // E edges

    float2* out = (float2*)d_out;

    int P = (n + S_NODES - 1) / S_NODES;

    // ws layout: [cnts PMAX*BK*4] [totals PMAX*4] [starts (PMAX+1)*4] [buckets e*4]
    size_t off_totals = (size_t)PMAX * BK * sizeof(int);
    size_t off_starts = off_totals + PMAX * sizeof(int);
    size_t off_buckets = (off_starts + (PMAX + 1) * sizeof(int) + 255) & ~(size_t)255;
    size_t need = off_buckets + (size_t)e * sizeof(int);

    // s must fit 24 bits for the (s<<8 | d_local) packing
    if (P <= PMAX && n < (1 << 24) && ws_size >= need) {
        int* cnts = (int*)d_ws;
        int* totals = (int*)((char*)d_ws + off_totals);
        int* starts = (int*)((char*)d_ws + off_starts);
        int* buckets = (int*)((char*)d_ws + off_buckets);

        int e4 = e >> 2;
        int chunk = (e4 + BK - 1) / BK;      // int4 groups per block

        count_kernel<<<BK, BK_THREADS, 0, stream>>>(
            (const int4*)dst, dst, cnts, e, chunk);
        colscan_kernel<<<(PMAX * 64) / 1024, 1024, 0, stream>>>(cnts, totals);
        prefix_kernel<<<1, PMAX, 0, stream>>>(totals, starts);
        scatter_kernel<<<BK, BK_THREADS, 0, stream>>>(
            (const int4*)src, (const int4*)dst, src, dst,
            cnts, starts, buckets, e, chunk);
        scan_kernel<<<P, 1024, 0, stream>>>(
            x, v, buckets, starts, out, n);
    } else {
        // fallback: direct atomics
        int threads = 256;
        init_out_kernel<<<(n + threads - 1) / threads, threads, 0, stream>>>(
            v, out, n);
        int e4 = e / 4;
        int blocks = (e4 + threads - 1) / threads;
        if (blocks < 1) blocks = 1;
        edge_kernel_atomic<<<blocks, threads, 0, stream>>>(
            x, (const int4*)src, (const int4*)dst, src, dst, (float*)out, e4, e);
    }
}

// Round 8
// 132.828 us; speedup vs baseline: 22.3141x; 1.0456x over previous
//
#include <hip/hip_runtime.h>

#define GAMMA 0.1f
#define EPS_F 1e-12f

// ---- partition config ----
// S_NODES=1600 -> d_local fits 11 bits; s (<2^17) packed above: 28 bits/edge.
// P = ceil(100000/1600) = 63. Scatter runs per (block,partition) ~200 edges
// = 800 B contiguous -> no HBM write amplification (round-7's S_NODES=200 had
// ~100 B runs -> ~16x line-granule amplification on 12.8 MB of scattered 4B
// stores, thrashing the 4 MB per-XCD L2).
#define S_NODES 1600
#define PMAX 64           // power of two >= P
#define BK 256            // count/scatter grid
#define BK_THREADS 1024
#define SCAN_B 8          // scan blocks per partition
#define SCAN_THREADS 256

// ---------------- 1) per-block per-partition histogram ----------------------
// cnts layout: [k][b] (column-contiguous) so column scan reads coalesced.
__global__ __launch_bounds__(BK_THREADS)
void count_kernel(const int4* __restrict__ dst4, const int* __restrict__ dst,
                  int* __restrict__ cnts, int e, int chunk) {
    __shared__ int hist[PMAX];
    int tid = threadIdx.x, b = blockIdx.x;
    if (tid < PMAX) hist[tid] = 0;
    __syncthreads();
    int e4 = e >> 2;
    long gs = (long)b * chunk;
    long ge = gs + chunk; if (ge > e4) ge = e4;
    for (long i = gs + tid; i < ge; i += BK_THREADS) {
        int4 d4 = dst4[i];
        atomicAdd(&hist[d4.x / S_NODES], 1);
        atomicAdd(&hist[d4.y / S_NODES], 1);
        atomicAdd(&hist[d4.z / S_NODES], 1);
        atomicAdd(&hist[d4.w / S_NODES], 1);
    }
    if (b == BK - 1) {                       // tail edges (e % 4)
        for (int i = e4 * 4 + tid; i < e; i += BK_THREADS)
            atomicAdd(&hist[dst[i] / S_NODES], 1);
    }
    __syncthreads();
    if (tid < PMAX) cnts[(long)tid * BK + b] = hist[tid];
}

// ---------------- 2) fused column-scan + cross-partition prefix -------------
// One block, 1024 threads (16 waves). Wave w scans columns w, w+16, ...
// (each column = 256 ints = 64 lanes x int4), rewriting cnts to per-block
// LOCAL bases and collecting column totals; then a PMAX-wide Hillis-Steele
// produces starts[].
__global__ __launch_bounds__(1024)
void scanoff_kernel(int* __restrict__ cnts, int* __restrict__ starts) {
    __shared__ int sc[PMAX];
    int tid = threadIdx.x;
    int wave = tid >> 6, lane = tid & 63;
    for (int col = wave; col < PMAX; col += 16) {
        int4* colp = (int4*)(cnts + (long)col * BK);
        int4 vv = colp[lane];
        int lt = vv.x + vv.y + vv.z + vv.w;
        int inc = lt;
        #pragma unroll
        for (int off = 1; off < 64; off <<= 1) {
            int t = __shfl_up(inc, off);
            if (lane >= off) inc += t;
        }
        int ex = inc - lt;
        int4 bb;
        bb.x = ex;
        bb.y = ex + vv.x;
        bb.z = ex + vv.x + vv.y;
        bb.w = ex + vv.x + vv.y + vv.z;
        colp[lane] = bb;                     // per-block local bases
        if (lane == 63) sc[col] = inc;       // column total
    }
    __syncthreads();
    int tot = (tid < PMAX) ? sc[tid] : 0;
    for (int off = 1; off < PMAX; off <<= 1) {
        int vv = (tid < PMAX && tid >= off) ? sc[tid - off] : 0;
        __syncthreads();
        if (tid < PMAX) sc[tid] += vv;
        __syncthreads();
    }
    if (tid < PMAX) {
        starts[tid] = sc[tid] - tot;         // exclusive prefix
        if (tid == PMAX - 1) starts[PMAX] = sc[tid];   // == e
    }
}

// ---------------- 3) perfect-pack scatter (packed 4B edges) -----------------
__device__ __forceinline__ void scatter_one(int s, int d, int* loff,
                                            int* __restrict__ buckets) {
    int p = d / S_NODES;
    int r = atomicAdd(&loff[p], 1);          // LDS rank
    buckets[r] = (s << 11) | (d - p * S_NODES);
}

__global__ __launch_bounds__(BK_THREADS)
void scatter_kernel(const int4* __restrict__ src4, const int4* __restrict__ dst4,
                    const int* __restrict__ src, const int* __restrict__ dst,
                    const int* __restrict__ cnts, const int* __restrict__ starts,
                    int* __restrict__ buckets, int e, int chunk) {
    __shared__ int loff[PMAX];
    int tid = threadIdx.x, b = blockIdx.x;
    if (tid < PMAX)
        loff[tid] = cnts[(long)tid * BK + b] + starts[tid];   // absolute base
    __syncthreads();
    int e4 = e >> 2;
    long gs = (long)b * chunk;
    long ge = gs + chunk; if (ge > e4) ge = e4;
    for (long i = gs + tid; i < ge; i += BK_THREADS) {
        int4 s4 = src4[i];
        int4 d4 = dst4[i];
        scatter_one(s4.x, d4.x, loff, buckets);
        scatter_one(s4.y, d4.y, loff, buckets);
        scatter_one(s4.z, d4.z, loff, buckets);
        scatter_one(s4.w, d4.w, loff, buckets);
    }
    if (b == BK - 1) {                       // tail edges: same block as count
        for (int i = e4 * 4 + tid; i < e; i += BK_THREADS)
            scatter_one(src[i], dst[i], loff, buckets);
    }
}

// ---------------- 4) dense scan: SCAN_B blocks per partition ----------------
__global__ __launch_bounds__(SCAN_THREADS)
void scan_kernel(const float2* __restrict__ x,
                 const int* __restrict__ buckets, const int* __restrict__ starts,
                 float2* __restrict__ partials) {
    __shared__ float2 acc[S_NODES];          // 12.8 KB
    int p = blockIdx.x / SCAN_B;
    int b = blockIdx.x - p * SCAN_B;
    int lo = p * S_NODES;
    int tid = threadIdx.x;
    for (int i = tid; i < S_NODES; i += SCAN_THREADS)
        acc[i] = make_float2(0.f, 0.f);
    __syncthreads();
    int s0 = starts[p], s1 = starts[p + 1];
    int len = s1 - s0;
    int ch = (len + SCAN_B - 1) / SCAN_B;
    int a0 = s0 + b * ch;
    int a1 = a0 + ch; if (a1 > s1) a1 = s1;
    for (int i = a0 + tid; i < a1; i += SCAN_THREADS) {
        int w = buckets[i];                  // coalesced 4B packed edge
        int s = ((unsigned)w) >> 11;
        int dl = w & 2047;
        float2 xs = x[s];                    // random, L2-resident (800 KB)
        float2 xd = x[lo + dl];              // 12.8 KB window
        float dx = xd.x - xs.x;
        float dy = xd.y - xs.y;
        float r = sqrtf(dx * dx + dy * dy);
        float sc = -2.0f * (r - 1.0f) / fmaxf(r, EPS_F);
        atomicAdd(&acc[dl].x, sc * dx);
        atomicAdd(&acc[dl].y, sc * dy);
    }
    __syncthreads();
    float2* wsb = partials + (size_t)blockIdx.x * S_NODES;
    for (int i = tid; i < S_NODES; i += SCAN_THREADS)
        wsb[i] = acc[i];
}

// ---------------- 5) reduce over SCAN_B partials + damping ------------------
__global__ __launch_bounds__(256)
void reduce_kernel(const float2* __restrict__ partials,
                   const float2* __restrict__ v,
                   float2* __restrict__ out, int n) {
    int i = blockIdx.x * blockDim.x + threadIdx.x;
    if (i >= n) return;
    int p = i / S_NODES;
    int loc = i - p * S_NODES;
    const float2* base = partials + ((size_t)(p * SCAN_B) * S_NODES + loc);
    float2 t0 = base[0 * S_NODES];
    float2 t1 = base[1 * S_NODES];
    float2 t2 = base[2 * S_NODES];
    float2 t3 = base[3 * S_NODES];
    float2 t4 = base[4 * S_NODES];
    float2 t5 = base[5 * S_NODES];
    float2 t6 = base[6 * S_NODES];
    float2 t7 = base[7 * S_NODES];
    float sx = ((t0.x + t1.x) + (t2.x + t3.x)) + ((t4.x + t5.x) + (t6.x + t7.x));
    float sy = ((t0.y + t1.y) + (t2.y + t3.y)) + ((t4.y + t5.y) + (t6.y + t7.y));
    float2 vi = v[i];
    out[i] = make_float2(sx - GAMMA * vi.x, sy - GAMMA * vi.y);
}

// ---------------- fallback: direct global atomics ---------------------------
__global__ void init_out_kernel(const float2* __restrict__ v,
                                float2* __restrict__ out, int n) {
    int i = blockIdx.x * blockDim.x + threadIdx.x;
    if (i < n) {
        float2 vi = v[i];
        out[i] = make_float2(-GAMMA * vi.x, -GAMMA * vi.y);
    }
}

__device__ __forceinline__ void do_edge_atomic(const float2* __restrict__ x,
                                               int s, int d,
                                               float* __restrict__ out) {
    float2 xs = x[s];
    float2 xd = x[d];
    float dx = xd.x - xs.x;
    float dy = xd.y - xs.y;
    float r = sqrtf(dx * dx + dy * dy);
    float sc = -2.0f * (r - 1.0f) / fmaxf(r, EPS_F);
    atomicAdd(&out[2 * d], sc * dx);
    atomicAdd(&out[2 * d + 1], sc * dy);
}

__global__ void edge_kernel_atomic(const float2* __restrict__ x,
                                   const int4* __restrict__ src4,
                                   const int4* __restrict__ dst4,
                                   const int* __restrict__ src,
                                   const int* __restrict__ dst,
                                   float* __restrict__ out,
                                   int e4, int e_total) {
    int i = blockIdx.x * blockDim.x + threadIdx.x;
    if (i < e4) {
        int4 s = src4[i];
        int4 d = dst4[i];
        do_edge_atomic(x, s.x, d.x, out);
        do_edge_atomic(x, s.y, d.y, out);
        do_edge_atomic(x, s.z, d.z, out);
        do_edge_atomic(x, s.w, d.w, out);
    }
    if (i == 0) {
        for (int ee = e4 * 4; ee < e_total; ++ee)
            do_edge_atomic(x, src[ee], dst[ee], out);
    }
}

extern "C" void kernel_launch(void* const* d_in, const int* in_sizes, int n_in,
                              void* d_out, int out_size, void* d_ws, size_t ws_size,
                              hipStream_t stream) {
    const float2* x = (const float2*)d_in[0];   // [N,2] fp32
    const float2* v = (const float2*)d_in[1];   // [N,2] fp32
    const int* src  = (const int*)d_in[2];      // [E] int32
    const int* dst  = (const int*)d_in[3];      // [E] int32

    int n = in_sizes[0] / 2;   // N nodes
    int e = in_sizes[2];       // E edges

    float2* out = (float2*)d_out;

    int P = (n + S_NODES - 1) / S_NODES;

    // ws layout: [cnts PMAX*BK*4] [starts (PMAX+1)*4] [buckets e*4] [partials]
    size_t off_starts = (size_t)PMAX * BK * sizeof(int);
    size_t off_buckets = (off_starts + (PMAX + 1) * sizeof(int) + 255) & ~(size_t)255;
    size_t off_part = (off_buckets + (size_t)e * sizeof(int) + 255) & ~(size_t)255;
    size_t need = off_part + (size_t)P * SCAN_B * S_NODES * sizeof(float2);

    // s must fit 21 bits for the (s<<11 | d_local) packing to stay positive
    if (P <= PMAX && n <= (1 << 20) && ws_size >= need) {
        int* cnts = (int*)d_ws;
        int* starts = (int*)((char*)d_ws + off_starts);
        int* buckets = (int*)((char*)d_ws + off_buckets);
        float2* partials = (float2*)((char*)d_ws + off_part);

        int e4 = e >> 2;
        int chunk = (e4 + BK - 1) / BK;      // int4 groups per block

        count_kernel<<<BK, BK_THREADS, 0, stream>>>(
            (const int4*)dst, dst, cnts, e, chunk);
        scanoff_kernel<<<1, 1024, 0, stream>>>(cnts, starts);
        scatter_kernel<<<BK, BK_THREADS, 0, stream>>>(
            (const int4*)src, (const int4*)dst, src, dst,
            cnts, starts, buckets, e, chunk);
        scan_kernel<<<P * SCAN_B, SCAN_THREADS, 0, stream>>>(
            x, buckets, starts, partials);
        reduce_kernel<<<(n + 255) / 256, 256, 0, stream>>>(
            partials, v, out, n);
    } else {
        // fallback: direct atomics
        int threads = 256;
        init_out_kernel<<<(n + threads - 1) / threads, threads, 0, stream>>>(
            v, out, n);
        int e4 = e / 4;
        int blocks = (e4 + threads - 1) / threads;
        if (blocks < 1) blocks = 1;
        edge_kernel_atomic<<<blocks, threads, 0, stream>>>(
            x, (const int4*)src, (const int4*)dst, src, dst, (float*)out, e4, e);
    }
}